// Round 8
// baseline (237.383 us; speedup 1.0000x reference)
//
#include <hip/hip_runtime.h>

constexpr int TT = 5;     // temporal length
constexpr int KK = 25;    // spatial neighbors
#define NEGV -1e10f

typedef _Float16 f16;
typedef __attribute__((ext_vector_type(8))) _Float16 f16x8;
typedef __attribute__((ext_vector_type(4))) _Float16 f16x4;
typedef __attribute__((ext_vector_type(4))) float f32x4;

// async global -> LDS direct copy, 16 B/lane (wave-uniform LDS base + lane*16)
__device__ __forceinline__ void gload16(const void* g, void* l) {
    __builtin_amdgcn_global_load_lds(
        (const __attribute__((address_space(1))) unsigned int*)g,
        (__attribute__((address_space(3))) unsigned int*)l, 16, 0, 0);
}

// bijective XCD-chunk remap (m204)
__device__ __forceinline__ int xcd_remap(int id, int G) {
    const int c = id & 7, j = id >> 3;
    const int q = G >> 3, r = G & 7;
    const int base = (c < r) ? c * (q + 1) : r * (q + 1) + (c - r) * q;
    return base + j;
}

// ---------------------------------------------------------------------------
// prep_all (ONE launch), block-range dispatch:
//   [0,64)    : transpose 4 weights (tWk,tWv,tWq,sWo) -> wt [z*256+n][k] fp16
//   [64,112)  : compose Wc = tWo @ sW{q,k,v}  (256k x 768n), write wc [n][k] fp16
//   112       : compose bias bcs[n] = tbo @ sW + sb
//   [113,...) : x f32 -> fp16 (grid-stride)
// ---------------------------------------------------------------------------
struct PrepAll {
    const float* Wt[4]; const float* bt[4];
    const float* tWo;   const float* tbo;
    const float* sW[3]; const float* sb[3];
};

__global__ __launch_bounds__(256) void prep_all(
    PrepAll pp, f16* __restrict__ wt, float* __restrict__ bc,
    f16* __restrict__ wc, float* __restrict__ bcs,
    const float* __restrict__ x, f16* __restrict__ xh, int n8)
{
    const int bid = blockIdx.x, t = threadIdx.x;

    if (bid < 64) {
        // ---- weight transpose -> fp16 [n][k] ----
        __shared__ float sT[64][65];
        const int z = bid >> 4, sub = bid & 15;
        const int k0 = (sub >> 2) * 64, n0 = (sub & 3) * 64;
        const float* W = pp.Wt[z];
        f16* wh = wt + (size_t)z * 65536;
        const int kk = t >> 2;
        #pragma unroll
        for (int c = 0; c < 4; ++c) {
            const int col = (t & 3) * 16 + c * 4;
            float4 v = *(const float4*)(W + (size_t)(k0 + kk) * 256 + n0 + col);
            sT[kk][col] = v.x; sT[kk][col + 1] = v.y;
            sT[kk][col + 2] = v.z; sT[kk][col + 3] = v.w;
        }
        __syncthreads();
        const int n = t >> 2, ks = (t & 3) * 16;
        f16* ph = wh + (size_t)(n0 + n) * 256 + k0 + ks;
        #pragma unroll
        for (int j0 = 0; j0 < 16; j0 += 8) {
            f16x8 vh;
            #pragma unroll
            for (int j = 0; j < 8; ++j) vh[j] = (f16)sT[ks + j0 + j][n];
            *(f16x8*)(ph + j0) = vh;
        }
        if (sub == 0) bc[z * 256 + t] = pp.bt[z][t];
    } else if (bid < 112) {
        // ---- composed weight: Wc[k][n] = sum_c tWo[k][c]*sW[c][n]; store wc[n][k] f16
        const int cb = bid - 64;
        const int m0 = (cb / 12) * 64;        // k-tile
        const int nt = cb % 12;               // n-tile (global cols nt*64)
        const int sel = nt >> 2;
        const int nc0 = (nt & 3) * 64;
        const float* Amat = pp.tWo;
        const float* Bmat = pp.sW[sel];
        __shared__ float sa[16][68];
        __shared__ float sbm[16][64];
        const int tm = t >> 4, tn = t & 15;
        const int r = t >> 2, cA = (t & 3) << 2;
        const int kB = t >> 4, jB = (t & 15) << 2;
        float acc[4][4] = {};
        for (int c0 = 0; c0 < 256; c0 += 16) {
            float4 a4 = *(const float4*)(Amat + (size_t)(m0 + r) * 256 + c0 + cA);
            float4 b4 = *(const float4*)(Bmat + (size_t)(c0 + kB) * 256 + nc0 + jB);
            __syncthreads();
            sa[cA + 0][r] = a4.x; sa[cA + 1][r] = a4.y;
            sa[cA + 2][r] = a4.z; sa[cA + 3][r] = a4.w;
            *(float4*)(&sbm[kB][jB]) = b4;
            __syncthreads();
            #pragma unroll
            for (int k = 0; k < 16; ++k) {
                float4 a = *(const float4*)(&sa[k][tm * 4]);
                float4 b = *(const float4*)(&sbm[k][tn * 4]);
                acc[0][0] += a.x * b.x; acc[0][1] += a.x * b.y; acc[0][2] += a.x * b.z; acc[0][3] += a.x * b.w;
                acc[1][0] += a.y * b.x; acc[1][1] += a.y * b.y; acc[1][2] += a.y * b.z; acc[1][3] += a.y * b.w;
                acc[2][0] += a.z * b.x; acc[2][1] += a.z * b.y; acc[2][2] += a.z * b.z; acc[2][3] += a.z * b.w;
                acc[3][0] += a.w * b.x; acc[3][1] += a.w * b.y; acc[3][2] += a.w * b.z; acc[3][3] += a.w * b.w;
            }
        }
        const int ng0 = nt * 64 + tn * 4;
        #pragma unroll
        for (int i = 0; i < 4; ++i)
            #pragma unroll
            for (int j = 0; j < 4; ++j)
                wc[(size_t)(ng0 + j) * 256 + m0 + tm * 4 + i] = (f16)acc[i][j];
    } else if (bid == 112) {
        // ---- composed bias ----
        #pragma unroll
        for (int rgn = 0; rgn < 3; ++rgn) {
            const float* B = pp.sW[rgn];
            float a = 0.f;
            for (int c = 0; c < 256; ++c) a += pp.tbo[c] * B[(size_t)c * 256 + t];
            bcs[rgn * 256 + t] = a + pp.sb[rgn][t];
        }
    } else {
        // ---- x -> fp16 ----
        for (int i = (bid - 113) * 256 + t; i < n8; i += 2048 * 256) {
            const float4 a = ((const float4*)x)[2 * i];
            const float4 b = ((const float4*)x)[2 * i + 1];
            f16x8 o;
            o[0] = (f16)a.x; o[1] = (f16)a.y; o[2] = (f16)a.z; o[3] = (f16)a.w;
            o[4] = (f16)b.x; o[5] = (f16)b.y; o[6] = (f16)b.z; o[7] = (f16)b.w;
            *(f16x8*)(xh + (size_t)i * 8) = o;
        }
    }
}

// ---------------------------------------------------------------------------
// fp16 MFMA GEMM, 2-job launch. Tile 128x128, BK=64, double-buffered LDS,
// 1 barrier/K-step, XOR swizzle (inverse-swizzled global source + swizzled
// ds_read), gload_lds staging, XCD remap over the whole grid.
// Job: C = A[M x 256 (lda)] @ W^T[n][k] + bias; f16 out (C16) or f32 (C32).
// ---------------------------------------------------------------------------
struct GJob {
    const f16* A; const f16* W; const float* bias;
    f16* C16; float* C32;
    int lda, M, ldc, GY, nblk;
};

__global__ __launch_bounds__(512, 4) void gemm_f16(GJob j0, GJob j1, int G)
{
    __shared__ f16 sA[2][128 * 64];
    __shared__ f16 sB[2][128 * 64];

    const int tid = threadIdx.x;
    const int l   = tid & 63, w = tid >> 6;
    const int l15 = l & 15, l4 = l >> 4;
    const int wm  = w >> 2, wn = w & 3;

    int p = xcd_remap(blockIdx.x, G);
    const bool first = (p < j0.nblk);
    const GJob jb = first ? j0 : j1;
    if (!first) p -= j0.nblk;

    const int bm = (p / jb.GY) * 128;
    const int bn = (p % jb.GY) * 128;

    // staging source (inverse-swizzled col-group so swizzled reads see linear data)
    const int srow8 = l >> 3;
    const int scol  = ((l & 7) ^ srow8) * 8;
    size_t aoff[2];
    #pragma unroll
    for (int j = 0; j < 2; ++j) {
        int r = bm + (w * 2 + j) * 8 + srow8;
        if (r > jb.M - 1) r = jb.M - 1;          // clamp reads; stores guarded
        aoff[j] = (size_t)r * jb.lda + scol;
    }
    size_t boff[2];
    #pragma unroll
    for (int j = 0; j < 2; ++j)
        boff[j] = (size_t)(bn + (w * 2 + j) * 8 + srow8) * 256 + scol;

    f32x4 acc[4][2];
    #pragma unroll
    for (int i = 0; i < 4; ++i)
        #pragma unroll
        for (int j = 0; j < 2; ++j) acc[i][j] = f32x4{0.f, 0.f, 0.f, 0.f};

    auto STAGE = [&](int buf, int k0) {
        #pragma unroll
        for (int j = 0; j < 2; ++j)
            gload16(jb.A + aoff[j] + k0, &sA[buf][(w * 2 + j) * 512]);
        #pragma unroll
        for (int j = 0; j < 2; ++j)
            gload16(jb.W + boff[j] + k0, &sB[buf][(w * 2 + j) * 512]);
    };

    STAGE(0, 0);
    __syncthreads();

    const int swz = l15 & 7;
    #pragma unroll
    for (int t = 0; t < 4; ++t) {
        if (t < 3) STAGE((t + 1) & 1, (t + 1) * 64);

        f16x8 af[4][2], bf[2][2];
        #pragma unroll
        for (int mf = 0; mf < 4; ++mf) {
            const int r = wm * 64 + mf * 16 + l15;
            #pragma unroll
            for (int ks = 0; ks < 2; ++ks)
                af[mf][ks] = *(const f16x8*)&sA[t & 1][r * 64 + (((ks * 4 + l4) ^ swz) * 8)];
        }
        #pragma unroll
        for (int nf = 0; nf < 2; ++nf) {
            const int r = wn * 32 + nf * 16 + l15;
            #pragma unroll
            for (int ks = 0; ks < 2; ++ks)
                bf[nf][ks] = *(const f16x8*)&sB[t & 1][r * 64 + (((ks * 4 + l4) ^ swz) * 8)];
        }
        #pragma unroll
        for (int mf = 0; mf < 4; ++mf)
            #pragma unroll
            for (int nf = 0; nf < 2; ++nf)
                #pragma unroll
                for (int ks = 0; ks < 2; ++ks)
                    acc[mf][nf] = __builtin_amdgcn_mfma_f32_16x16x32_f16(
                        af[mf][ks], bf[nf][ks], acc[mf][nf], 0, 0, 0);
        __syncthreads();
    }

    #pragma unroll
    for (int mf = 0; mf < 4; ++mf) {
        const int row0 = bm + wm * 64 + mf * 16 + l4 * 4;
        #pragma unroll
        for (int nf = 0; nf < 2; ++nf) {
            const int col = bn + wn * 32 + nf * 16 + l15;
            const float bs = jb.bias[col];
            #pragma unroll
            for (int i = 0; i < 4; ++i) {
                const int row = row0 + i;
                if (row < jb.M) {
                    const float v = acc[mf][nf][i] + bs;
                    const size_t o = (size_t)row * jb.ldc + col;
                    if (jb.C32) jb.C32[o] = v;
                    else        jb.C16[o] = (f16)v;
                }
            }
        }
    }
}

// ---------------------------------------------------------------------------
// Temporal attention, wave-per-node: lane = (h, dq), 4 d-elems per lane.
// ---------------------------------------------------------------------------
__global__ __launch_bounds__(256) void attn_t(
    const f16* __restrict__ q, const f16* __restrict__ kv,
    const int* __restrict__ tmask, f16* __restrict__ ctx)
{
    const int tid = threadIdx.x;
    const int wv = tid >> 6, l = tid & 63;
    const int n = blockIdx.x * 4 + wv;
    const int col = ((l >> 3) * 32) + (l & 7) * 4;
    const float scale = 0.1767766952966369f;

    const f16x4 qv = *(const f16x4*)(q + (size_t)n * 256 + col);
    const float q0 = (float)qv[0], q1 = (float)qv[1], q2 = (float)qv[2], q3 = (float)qv[3];

    float m = -3.0e38f, lsum = 0.f;
    float a0 = 0.f, a1 = 0.f, a2 = 0.f, a3 = 0.f;
    #pragma unroll
    for (int t = 0; t < TT; ++t) {
        const size_t row = ((size_t)n * TT + t) * 512;
        const f16x4 kk = *(const f16x4*)(kv + row + col);
        const f16x4 vv = *(const f16x4*)(kv + row + 256 + col);
        float p = q0 * (float)kk[0] + q1 * (float)kk[1]
                + q2 * (float)kk[2] + q3 * (float)kk[3];
        p += __shfl_xor(p, 1);
        p += __shfl_xor(p, 2);
        p += __shfl_xor(p, 4);
        const float s  = (tmask[n * TT + t] == 0) ? NEGV : p * scale;
        const float mn = fmaxf(m, s);
        const float sc = exp2f((m - mn) * 1.44269504f);
        const float pe = exp2f((s - mn) * 1.44269504f);
        lsum = lsum * sc + pe;
        a0 = a0 * sc + pe * (float)vv[0];
        a1 = a1 * sc + pe * (float)vv[1];
        a2 = a2 * sc + pe * (float)vv[2];
        a3 = a3 * sc + pe * (float)vv[3];
        m = mn;
    }
    const float inv = 1.0f / lsum;
    f16x4 o;
    o[0] = (f16)(a0 * inv); o[1] = (f16)(a1 * inv);
    o[2] = (f16)(a2 * inv); o[3] = (f16)(a3 * inv);
    *(f16x4*)(ctx + (size_t)n * 256 + col) = o;
}

// ---------------------------------------------------------------------------
// Spatial attention, wave-per-node; XCD-chunk remap for neighbor L2 locality.
// ---------------------------------------------------------------------------
__global__ __launch_bounds__(256) void attn_s(
    const f16* __restrict__ sqkv, const int* __restrict__ nbrs,
    const int* __restrict__ smask, f16* __restrict__ sctx, int G)
{
    __shared__ int nbL[4 * KK];
    __shared__ int mkL[4 * KK];
    const int tid = threadIdx.x;
    const int nbase = xcd_remap(blockIdx.x, G) * 4;
    if (tid < 4 * KK) {
        nbL[tid] = nbrs[nbase * KK + tid];
        mkL[tid] = smask[nbase * KK + tid];
    }
    __syncthreads();

    const int wv = tid >> 6, l = tid & 63;
    const int n = nbase + wv;
    const int col = ((l >> 3) * 32) + (l & 7) * 4;
    const float scale = 0.1767766952966369f;

    const f16x4 qv = *(const f16x4*)(sqkv + (size_t)n * 768 + col);
    const float q0 = (float)qv[0], q1 = (float)qv[1], q2 = (float)qv[2], q3 = (float)qv[3];

    float m = -3.0e38f, lsum = 0.f;
    float a0 = 0.f, a1 = 0.f, a2 = 0.f, a3 = 0.f;
    #pragma unroll
    for (int j = 0; j < KK; ++j) {
        const size_t row = (size_t)nbL[wv * KK + j] * 768;
        const f16x4 kk = *(const f16x4*)(sqkv + row + 256 + col);
        const f16x4 vv = *(const f16x4*)(sqkv + row + 512 + col);
        float p = q0 * (float)kk[0] + q1 * (float)kk[1]
                + q2 * (float)kk[2] + q3 * (float)kk[3];
        p += __shfl_xor(p, 1);
        p += __shfl_xor(p, 2);
        p += __shfl_xor(p, 4);
        const float s  = (mkL[wv * KK + j] == 0) ? NEGV : p * scale;
        const float mn = fmaxf(m, s);
        const float sc = exp2f((m - mn) * 1.44269504f);
        const float pe = exp2f((s - mn) * 1.44269504f);
        lsum = lsum * sc + pe;
        a0 = a0 * sc + pe * (float)vv[0];
        a1 = a1 * sc + pe * (float)vv[1];
        a2 = a2 * sc + pe * (float)vv[2];
        a3 = a3 * sc + pe * (float)vv[3];
        m = mn;
    }
    const float inv = 1.0f / lsum;
    f16x4 o;
    o[0] = (f16)(a0 * inv); o[1] = (f16)(a1 * inv);
    o[2] = (f16)(a2 * inv); o[3] = (f16)(a3 * inv);
    *(f16x4*)(sctx + (size_t)n * 256 + col) = o;
}

// ---------------------------------------------------------------------------
extern "C" void kernel_launch(void* const* d_in, const int* in_sizes, int n_in,
                              void* d_out, int out_size, void* d_ws, size_t ws_size,
                              hipStream_t stream)
{
    const float* x = (const float*)d_in[0];
    const int* nbrs  = (const int*)d_in[17];
    const int* tmask = (const int*)d_in[18];
    const int* smask = (const int*)d_in[19];
    float* out = (float*)d_out;

    const int N  = in_sizes[0] / (TT * 256);  // 10000
    const int MT = N * TT;                    // 50000

    // ---- workspace layout (~99 MB peak) ----
    f16* wt  = (f16*)d_ws;                           // [1024][256]
    f16* wc  = wt + (size_t)1024 * 256;              // [768][256]
    float* bc  = (float*)(wc + (size_t)768 * 256);   // [1024]
    float* bcs = bc + 1024;                          // [768]
    f16* xh     = (f16*)(bcs + 768);                 // [MT*256]
    f16* kvbuf  = xh + (size_t)MT * 256;             // [MT*512]
    f16* q16    = kvbuf + (size_t)MT * 512;          // [N*256]
    f16* ctx    = q16 + (size_t)N * 256;             // [N*256]
    f16* sqkv16 = ctx + (size_t)N * 256;             // [N*768]
    f16* sctx   = sqkv16 + (size_t)N * 768;          // [N*256]

    // wt rows: tWk=[0,256) tWv=[256,512) tWq=[512,768) sWo=[768,1024)
    PrepAll pp;
    pp.Wt[0] = (const float*)d_in[3];  pp.bt[0] = (const float*)d_in[4];   // tWk
    pp.Wt[1] = (const float*)d_in[5];  pp.bt[1] = (const float*)d_in[6];   // tWv
    pp.Wt[2] = (const float*)d_in[1];  pp.bt[2] = (const float*)d_in[2];   // tWq
    pp.Wt[3] = (const float*)d_in[15]; pp.bt[3] = (const float*)d_in[16];  // sWo
    pp.tWo   = (const float*)d_in[7];  pp.tbo   = (const float*)d_in[8];
    pp.sW[0] = (const float*)d_in[9];  pp.sb[0] = (const float*)d_in[10];  // sWq
    pp.sW[1] = (const float*)d_in[11]; pp.sb[1] = (const float*)d_in[12];  // sWk
    pp.sW[2] = (const float*)d_in[13]; pp.sb[2] = (const float*)d_in[14];  // sWv

    prep_all<<<113 + 2048, 256, 0, stream>>>(pp, wt, bc, wc, bcs, x, xh, MT * 256 / 8);

    const int GBM_T = (MT + 127) / 128;   // 391
    const int GBM_N = (N + 127) / 128;    // 79

    GJob jkv  = { xh, wt, bc, kvbuf, nullptr, 256, MT, 512, 4, GBM_T * 4 };
    GJob jq   = { xh + 4 * 256, wt + (size_t)512 * 256, bc + 512,
                  q16, nullptr, TT * 256, N, 256, 2, GBM_N * 2 };
    GJob jsq  = { ctx, wc, bcs, sqkv16, nullptr, 256, N, 768, 6, GBM_N * 6 };
    GJob jout = { sctx, wt + (size_t)768 * 256, bc + 768,
                  nullptr, out, 256, N, 256, 2, GBM_N * 2 };

    // kv + q projections fused in one launch (independent jobs)
    gemm_f16<<<jkv.nblk + jq.nblk, 512, 0, stream>>>(jkv, jq, jkv.nblk + jq.nblk);
    // temporal attention -> ctx fp16
    attn_t<<<N / 4, 256, 0, stream>>>(q16, kvbuf, tmask, ctx);
    // composed spatial q/k/v projection: sqkv = ctx @ Wc + bcs
    gemm_f16<<<jsq.nblk, 512, 0, stream>>>(jsq, jsq, jsq.nblk);
    // spatial attention -> sctx fp16 (XCD-chunked)
    attn_s<<<N / 4, 256, 0, stream>>>(sqkv16, nbrs, smask, sctx, N / 4);
    // output projection -> f32 out
    gemm_f16<<<jout.nblk, 512, 0, stream>>>(jout, jout, jout.nblk);
}